// Round 1
// baseline (1439.429 us; speedup 1.0000x reference)
//
#include <hip/hip_runtime.h>
#include <cstdint>
#include <cstddef>

typedef short bf16x8 __attribute__((ext_vector_type(8)));
typedef float f32x4 __attribute__((ext_vector_type(4)));
typedef unsigned short us4 __attribute__((ext_vector_type(4)));

#define DEV static __device__ __forceinline__

DEV unsigned short f2bf(float f) {
  union { float f; unsigned u; } v; v.f = f;
  unsigned r = v.u + 0x7FFFu + ((v.u >> 16) & 1u);
  return (unsigned short)(r >> 16);
}

DEV void gll16(const void* g, void* l) {
  __builtin_amdgcn_global_load_lds((const __attribute__((address_space(1))) void*)g,
                                   (__attribute__((address_space(3))) void*)l,
                                   16, 0, 0);
}

// ---------------------------------------------------------------------------
// Embedding: h = tok_emb[x] + pos_emb  -> f32 residual + bf16 copy
// ---------------------------------------------------------------------------
__global__ __launch_bounds__(256) void embed_kernel(
    const int* __restrict__ x, const float* __restrict__ te,
    const float* __restrict__ pe, float* __restrict__ hf,
    unsigned short* __restrict__ hb) {
  int row = blockIdx.x;          // 0..2047  (b*1024 + t)
  int t = row & 1023;
  int tok = x[row];
  int tid = threadIdx.x;
  float4 v = ((const float4*)(te + (size_t)tok * 1024))[tid];
  float4 p = ((const float4*)(pe + (size_t)t * 1024))[tid];
  v.x += p.x; v.y += p.y; v.z += p.z; v.w += p.w;
  ((float4*)(hf + (size_t)row * 1024))[tid] = v;
  us4 bv; bv[0] = f2bf(v.x); bv[1] = f2bf(v.y); bv[2] = f2bf(v.z); bv[3] = f2bf(v.w);
  ((us4*)(hb + (size_t)row * 1024))[tid] = bv;
}

// ---------------------------------------------------------------------------
// Weight transpose + f32->bf16: W[K][N] -> Wt[N][K]
// ---------------------------------------------------------------------------
__global__ __launch_bounds__(256) void wconv_kernel(
    const float* __restrict__ W, unsigned short* __restrict__ Wt, int K, int N) {
  __shared__ float tile[32][33];
  int n0 = blockIdx.x * 32, k0 = blockIdx.y * 32;
  int tx = threadIdx.x & 31, ty = threadIdx.x >> 5;  // ty 0..7
#pragma unroll
  for (int i = 0; i < 4; ++i)
    tile[ty * 4 + i][tx] = W[(size_t)(k0 + ty * 4 + i) * N + n0 + tx];
  __syncthreads();
#pragma unroll
  for (int i = 0; i < 4; ++i)
    Wt[(size_t)(n0 + ty * 4 + i) * K + k0 + tx] = f2bf(tile[tx][ty * 4 + i]);
}

// ---------------------------------------------------------------------------
// GEMM: C[M][N] = A[M][K](bf16) @ Bt[N][K](bf16)^T + bias
// BM=128, BK=64, 256 threads = 4 waves (2x2), 16x16x32 bf16 MFMA.
// EPI: 0=f32 out, 1=bf16 out, 2=relu->bf16, 3=bf16 to V^T layout [B*H*64][T]
// ---------------------------------------------------------------------------
template <int BN, int EPI>
__global__ __launch_bounds__(256) void gemm_kernel(
    const unsigned short* __restrict__ A, const unsigned short* __restrict__ Bt,
    const float* __restrict__ bias, void* __restrict__ Cout,
    int M, int N, int K) {
  constexpr int BM = 128, BK = 64;
  constexpr int NFR = BN / 32;              // n-frags per wave
  constexpr int AITERS = BM * BK / (8 * 256);
  constexpr int BITERS = BN * BK / (8 * 256);
  __shared__ unsigned short lA[BM * BK];
  __shared__ unsigned short lB[BN * BK];
  const int tid = threadIdx.x;
  const int wid = tid >> 6, lane = tid & 63;
  const int g = lane >> 4, c = lane & 15;
  const int wm = wid >> 1, wn = wid & 1;
  const int bm = blockIdx.x * BM;
  const int bn = blockIdx.y * BN;

  f32x4 acc[4][NFR];
#pragma unroll
  for (int mi = 0; mi < 4; ++mi)
#pragma unroll
    for (int ni = 0; ni < NFR; ++ni) acc[mi][ni] = f32x4{0.f, 0.f, 0.f, 0.f};

  for (int kb = 0; kb < K; kb += BK) {
#pragma unroll
    for (int it = 0; it < AITERS; ++it) {
      int chunk = it * 256 + tid;
      int row = chunk >> 3, cr = chunk & 7;
      int sc = cr ^ (row & 7);  // pre-swizzled source (rule #21)
      gll16(A + (size_t)(bm + row) * K + kb + sc * 8,
            lA + (size_t)(it * 256 + wid * 64) * 8);
    }
#pragma unroll
    for (int it = 0; it < BITERS; ++it) {
      int chunk = it * 256 + tid;
      int row = chunk >> 3, cr = chunk & 7;
      int sc = cr ^ (row & 7);
      gll16(Bt + (size_t)(bn + row) * K + kb + sc * 8,
            lB + (size_t)(it * 256 + wid * 64) * 8);
    }
    __syncthreads();
#pragma unroll
    for (int kk = 0; kk < 2; ++kk) {
      bf16x8 af[4], bfr[NFR];
#pragma unroll
      for (int mi = 0; mi < 4; ++mi) {
        int row = wm * 64 + mi * 16 + c;
        int ch = (kk * 4 + g) ^ (row & 7);
        af[mi] = *(const bf16x8*)(lA + row * BK + ch * 8);
      }
#pragma unroll
      for (int ni = 0; ni < NFR; ++ni) {
        int row = wn * (BN / 2) + ni * 16 + c;
        int ch = (kk * 4 + g) ^ (row & 7);
        bfr[ni] = *(const bf16x8*)(lB + row * BK + ch * 8);
      }
#pragma unroll
      for (int mi = 0; mi < 4; ++mi)
#pragma unroll
        for (int ni = 0; ni < NFR; ++ni)
          acc[mi][ni] = __builtin_amdgcn_mfma_f32_16x16x32_bf16(
              af[mi], bfr[ni], acc[mi][ni], 0, 0, 0);
    }
    __syncthreads();
  }

  // epilogue: C/D layout col=lane&15, row=(lane>>4)*4+reg
#pragma unroll
  for (int mi = 0; mi < 4; ++mi) {
    int row0 = bm + wm * 64 + mi * 16 + g * 4;
#pragma unroll
    for (int ni = 0; ni < NFR; ++ni) {
      int col = bn + wn * (BN / 2) + ni * 16 + c;
      float bv = bias[col];
#pragma unroll
      for (int r = 0; r < 4; ++r) {
        float v = acc[mi][ni][r] + bv;
        int row = row0 + r;
        if constexpr (EPI == 0) {
          ((float*)Cout)[(size_t)row * N + col] = v;
        } else if constexpr (EPI == 1) {
          ((unsigned short*)Cout)[(size_t)row * N + col] = f2bf(v);
        } else if constexpr (EPI == 2) {
          ((unsigned short*)Cout)[(size_t)row * N + col] = f2bf(fmaxf(v, 0.f));
        } else {  // V^T: [ (b*16+h)*64 + hd ][ t ]
          int b = row >> 10, t = row & 1023;
          int hh = col >> 6, hd = col & 63;
          ((unsigned short*)Cout)[(size_t)((b * 16 + hh) * 64 + hd) * 1024 + t] = f2bf(v);
        }
      }
    }
  }
}

// ---------------------------------------------------------------------------
// Flash attention: WG = (qblock of 64, head, batch), 4 waves x 16 q-rows.
// q,k: [B*T][D] bf16 ; vt: [B*H*64][T] bf16 ; o: [B*T][D] f32
// ---------------------------------------------------------------------------
__global__ __launch_bounds__(256) void attn_kernel(
    const unsigned short* __restrict__ q, const unsigned short* __restrict__ k,
    const unsigned short* __restrict__ vt, float* __restrict__ o) {
  __shared__ unsigned short lK[64 * 64];
  __shared__ unsigned short lV[64 * 64];
  __shared__ unsigned short lP[4][16 * 64];
  const int tid = threadIdx.x, wid = tid >> 6, lane = tid & 63;
  const int g = lane >> 4, c = lane & 15;
  const int qb = blockIdx.x * 64;
  const int h = blockIdx.y;
  const int b = blockIdx.z;
  const int qw = qb + wid * 16;

  // Q fragments (A-layout: m = lane&15, k = (lane>>4)*8+j)
  bf16x8 aq[2];
#pragma unroll
  for (int kk = 0; kk < 2; ++kk)
    aq[kk] = *(const bf16x8*)(q + (size_t)(b * 1024 + qw + c) * 1024 + h * 64 + kk * 32 + g * 8);

  float m_run[4], l_run[4];
  f32x4 acc_o[4];
#pragma unroll
  for (int r = 0; r < 4; ++r) { m_run[r] = -INFINITY; l_run[r] = 0.f; }
#pragma unroll
  for (int ni = 0; ni < 4; ++ni) acc_o[ni] = f32x4{0.f, 0.f, 0.f, 0.f};

  const int ntiles = qb / 64 + 1;
  for (int kt = 0; kt < ntiles; ++kt) {
    // stage K tile [tok][hd] and V^T tile [hd][tok], swizzled source chunks
#pragma unroll
    for (int it = 0; it < 2; ++it) {
      int chunk = it * 256 + tid;
      int row = chunk >> 3, cr = chunk & 7;
      int sc = cr ^ (row & 7);
      gll16(k + (size_t)(b * 1024 + kt * 64 + row) * 1024 + h * 64 + sc * 8,
            lK + (size_t)(it * 256 + wid * 64) * 8);
      gll16(vt + (size_t)((b * 16 + h) * 64 + row) * 1024 + kt * 64 + sc * 8,
            lV + (size_t)(it * 256 + wid * 64) * 8);
    }
    __syncthreads();

    // S = Q K^T
    f32x4 accs[4];
#pragma unroll
    for (int ni = 0; ni < 4; ++ni) accs[ni] = f32x4{0.f, 0.f, 0.f, 0.f};
#pragma unroll
    for (int kk = 0; kk < 2; ++kk)
#pragma unroll
      for (int ni = 0; ni < 4; ++ni) {
        int row = ni * 16 + c;
        int ch = (kk * 4 + g) ^ (row & 7);
        bf16x8 kf = *(const bf16x8*)(lK + row * 64 + ch * 8);
        accs[ni] = __builtin_amdgcn_mfma_f32_16x16x32_bf16(aq[kk], kf, accs[ni], 0, 0, 0);
      }

    // scale + causal mask + online softmax
    const bool diag = (kt == qb / 64);
    float p[4][4], rowmax[4];
#pragma unroll
    for (int r = 0; r < 4; ++r) rowmax[r] = -INFINITY;
#pragma unroll
    for (int ni = 0; ni < 4; ++ni)
#pragma unroll
      for (int r = 0; r < 4; ++r) {
        float s = accs[ni][r] * 0.125f;
        if (diag) {
          int ktok = kt * 64 + ni * 16 + c;
          int qtok = qw + g * 4 + r;
          if (ktok > qtok) s = -INFINITY;
        }
        p[ni][r] = s;
        rowmax[r] = fmaxf(rowmax[r], s);
      }
#pragma unroll
    for (int mm = 1; mm < 16; mm <<= 1)
#pragma unroll
      for (int r = 0; r < 4; ++r)
        rowmax[r] = fmaxf(rowmax[r], __shfl_xor(rowmax[r], mm, 64));

    float alpha[4];
#pragma unroll
    for (int r = 0; r < 4; ++r) {
      float mn = fmaxf(m_run[r], rowmax[r]);
      alpha[r] = __expf(m_run[r] - mn);
      m_run[r] = mn;
    }
#pragma unroll
    for (int ni = 0; ni < 4; ++ni)
#pragma unroll
      for (int r = 0; r < 4; ++r) p[ni][r] = __expf(p[ni][r] - m_run[r]);

    float rowsum[4];
#pragma unroll
    for (int r = 0; r < 4; ++r)
      rowsum[r] = p[0][r] + p[1][r] + p[2][r] + p[3][r];
#pragma unroll
    for (int mm = 1; mm < 16; mm <<= 1)
#pragma unroll
      for (int r = 0; r < 4; ++r) rowsum[r] += __shfl_xor(rowsum[r], mm, 64);
#pragma unroll
    for (int r = 0; r < 4; ++r) l_run[r] = l_run[r] * alpha[r] + rowsum[r];
#pragma unroll
    for (int ni = 0; ni < 4; ++ni)
#pragma unroll
      for (int r = 0; r < 4; ++r) acc_o[ni][r] *= alpha[r];

    // P -> per-wave LDS [q=16][tok=64], chunk swizzled by q&7
#pragma unroll
    for (int ni = 0; ni < 4; ++ni)
#pragma unroll
      for (int r = 0; r < 4; ++r) {
        int qrow = g * 4 + r;
        int tok = ni * 16 + c;
        int ch = (tok >> 3) ^ (qrow & 7);
        lP[wid][qrow * 64 + ch * 8 + (tok & 7)] = f2bf(p[ni][r]);
      }

    // O += P @ V
#pragma unroll
    for (int kk = 0; kk < 2; ++kk) {
      int chp = (kk * 4 + g) ^ (c & 7);
      bf16x8 pa = *(const bf16x8*)(&lP[wid][c * 64 + chp * 8]);
#pragma unroll
      for (int ni = 0; ni < 4; ++ni) {
        int row = ni * 16 + c;
        int ch = (kk * 4 + g) ^ (row & 7);
        bf16x8 vf = *(const bf16x8*)(lV + row * 64 + ch * 8);
        acc_o[ni] = __builtin_amdgcn_mfma_f32_16x16x32_bf16(pa, vf, acc_o[ni], 0, 0, 0);
      }
    }
    __syncthreads();
  }

#pragma unroll
  for (int ni = 0; ni < 4; ++ni)
#pragma unroll
    for (int r = 0; r < 4; ++r) {
      int row = b * 1024 + qw + g * 4 + r;
      int col = h * 64 + ni * 16 + c;
      o[(size_t)row * 1024 + col] = acc_o[ni][r] / l_run[r];
    }
}

// ---------------------------------------------------------------------------
// Fused residual-add + LayerNorm -> f32 + bf16
// ---------------------------------------------------------------------------
__global__ __launch_bounds__(256) void ln_add_kernel(
    const float* __restrict__ a, const float* __restrict__ res,
    const float* __restrict__ s, const float* __restrict__ bb,
    float* __restrict__ out_f, unsigned short* __restrict__ out_b) {
  int row = blockIdx.x, tid = threadIdx.x;
  float4 x = ((const float4*)(a + (size_t)row * 1024))[tid];
  float4 rv = ((const float4*)(res + (size_t)row * 1024))[tid];
  x.x += rv.x; x.y += rv.y; x.z += rv.z; x.w += rv.w;
  float sum = x.x + x.y + x.z + x.w;
  float sq = x.x * x.x + x.y * x.y + x.z * x.z + x.w * x.w;
#pragma unroll
  for (int mm = 1; mm < 64; mm <<= 1) {
    sum += __shfl_xor(sum, mm, 64);
    sq += __shfl_xor(sq, mm, 64);
  }
  __shared__ float ssum[4], ssq[4];
  int wid = tid >> 6, lane = tid & 63;
  if (lane == 0) { ssum[wid] = sum; ssq[wid] = sq; }
  __syncthreads();
  sum = ssum[0] + ssum[1] + ssum[2] + ssum[3];
  sq = ssq[0] + ssq[1] + ssq[2] + ssq[3];
  float mean = sum * (1.f / 1024.f);
  float var = sq * (1.f / 1024.f) - mean * mean;
  float rstd = rsqrtf(var + 1e-5f);
  float4 sv = ((const float4*)s)[tid];
  float4 bv = ((const float4*)bb)[tid];
  float4 y;
  y.x = (x.x - mean) * rstd * sv.x + bv.x;
  y.y = (x.y - mean) * rstd * sv.y + bv.y;
  y.z = (x.z - mean) * rstd * sv.z + bv.z;
  y.w = (x.w - mean) * rstd * sv.w + bv.w;
  ((float4*)(out_f + (size_t)row * 1024))[tid] = y;
  us4 ob; ob[0] = f2bf(y.x); ob[1] = f2bf(y.y); ob[2] = f2bf(y.z); ob[3] = f2bf(y.w);
  ((us4*)(out_b + (size_t)row * 1024))[tid] = ob;
}

// ---------------------------------------------------------------------------
extern "C" void kernel_launch(void* const* d_in, const int* in_sizes, int n_in,
                              void* d_out, int out_size, void* d_ws, size_t ws_size,
                              hipStream_t stream) {
  const int D = 1024, DFF = 4096, V = 32000, L = 6;
  const int* x = (const int*)d_in[0];
  const float* tok_emb = (const float*)d_in[1];
  const float* pos_emb = (const float*)d_in[2];
  const float* Wq = (const float*)d_in[3];  const float* bq = (const float*)d_in[4];
  const float* Wk = (const float*)d_in[5];  const float* bk = (const float*)d_in[6];
  const float* Wv = (const float*)d_in[7];  const float* bv = (const float*)d_in[8];
  const float* ln1s = (const float*)d_in[9];  const float* ln1b = (const float*)d_in[10];
  const float* W1 = (const float*)d_in[11];  const float* b1 = (const float*)d_in[12];
  const float* W2 = (const float*)d_in[13];  const float* b2 = (const float*)d_in[14];
  const float* ln2s = (const float*)d_in[15]; const float* ln2b = (const float*)d_in[16];
  const float* Wout = (const float*)d_in[17]; const float* bout = (const float*)d_in[18];

  char* ws = (char*)d_ws;
  float* h_res = (float*)(ws + 0);                     //  8 MB  [2048][1024] f32
  float* hi_res = (float*)(ws + 8388608);              //  8 MB
  float* tmp = (float*)(ws + 16777216);                //  8 MB
  unsigned short* hbf = (unsigned short*)(ws + 25165824);   // 4 MB bf16
  unsigned short* qb_ = (unsigned short*)(ws + 29360128);   // 4 MB
  unsigned short* kb_ = (unsigned short*)(ws + 33554432);   // 4 MB
  unsigned short* vtb = (unsigned short*)(ws + 37748736);   // 4 MB  V^T
  unsigned short* ffn1 = (unsigned short*)(ws + 41943040);  // 16 MB [2048][4096]
  unsigned short* wsc = (unsigned short*)(ws + 58720256);   // 65.5 MB weight scratch

  embed_kernel<<<2048, 256, 0, stream>>>(x, tok_emb, pos_emb, h_res, hbf);

  for (int l = 0; l < L; ++l) {
    // Q
    wconv_kernel<<<dim3(32, 32), 256, 0, stream>>>(Wq + (size_t)l * D * D, wsc, D, D);
    gemm_kernel<64, 1><<<dim3(16, 16), 256, 0, stream>>>(hbf, wsc, bq + l * D, qb_, 2048, D, D);
    // K
    wconv_kernel<<<dim3(32, 32), 256, 0, stream>>>(Wk + (size_t)l * D * D, wsc, D, D);
    gemm_kernel<64, 1><<<dim3(16, 16), 256, 0, stream>>>(hbf, wsc, bk + l * D, kb_, 2048, D, D);
    // V (writes transposed layout)
    wconv_kernel<<<dim3(32, 32), 256, 0, stream>>>(Wv + (size_t)l * D * D, wsc, D, D);
    gemm_kernel<64, 3><<<dim3(16, 16), 256, 0, stream>>>(hbf, wsc, bv + l * D, vtb, 2048, D, D);
    // attention
    attn_kernel<<<dim3(16, 16, 2), 256, 0, stream>>>(qb_, kb_, vtb, tmp);
    // hi = LN1(o + h)
    ln_add_kernel<<<2048, 256, 0, stream>>>(tmp, h_res, ln1s + l * D, ln1b + l * D, hi_res, hbf);
    // FFN1 (relu, bf16 out)
    wconv_kernel<<<dim3(128, 32), 256, 0, stream>>>(W1 + (size_t)l * D * DFF, wsc, D, DFF);
    gemm_kernel<128, 2><<<dim3(16, 32), 256, 0, stream>>>(hbf, wsc, b1 + l * DFF, ffn1, 2048, DFF, D);
    // FFN2 (f32 out)
    wconv_kernel<<<dim3(32, 128), 256, 0, stream>>>(W2 + (size_t)l * DFF * D, wsc, DFF, D);
    gemm_kernel<64, 0><<<dim3(16, 16), 256, 0, stream>>>(ffn1, wsc, b2 + l * D, tmp, 2048, D, DFF);
    // h = LN2(f + hi)
    ln_add_kernel<<<2048, 256, 0, stream>>>(tmp, hi_res, ln2s + l * D, ln2b + l * D, h_res, hbf);
  }

  // logits = h @ Wout + bout
  wconv_kernel<<<dim3(1000, 32), 256, 0, stream>>>(Wout, wsc, D, V);
  gemm_kernel<128, 0><<<dim3(16, 250), 256, 0, stream>>>(hbf, wsc, bout, (float*)d_out, 2048, V, D);
}